// Round 6
// baseline (535.643 us; speedup 1.0000x reference)
//
#include <hip/hip_runtime.h>
#include <hip/hip_bf16.h>

// Problem constants
#define BATCH   4
#define SEQ     2048
#define DMODEL  1024
#define NHEADS  16
#define DHEAD   64
#define BT      (BATCH*SEQ)   // 8192 tokens

typedef unsigned short u16;
typedef __bf16 bf16x8 __attribute__((ext_vector_type(8)));
typedef float  f32x4  __attribute__((ext_vector_type(4)));
typedef u16    u16x8  __attribute__((ext_vector_type(8)));

#define MFMA16(a,b,c) __builtin_amdgcn_mfma_f32_16x16x32_bf16((a),(b),(c),0,0,0)

__device__ __forceinline__ u16 f2b(float f) {
  return __builtin_bit_cast(u16, (__bf16)f);
}

__device__ __forceinline__ void gload_lds16(const u16* g, u16* l) {
  __builtin_amdgcn_global_load_lds(
      (const __attribute__((address_space(1))) void*)g,
      (__attribute__((address_space(3))) void*)l, 16, 0, 0);
}

// ---------------- elementwise f32 -> bf16 ----------------
__global__ __launch_bounds__(256) void cvt_bf16_kernel(
    const float* __restrict__ in, u16* __restrict__ out, int n8) {
  int i = blockIdx.x * 256 + threadIdx.x;
  if (i >= n8) return;
  const float4* p = (const float4*)(in + (long)i * 8);
  float4 a = p[0], b = p[1];
  u16x8 o;
  o[0]=f2b(a.x); o[1]=f2b(a.y); o[2]=f2b(a.z); o[3]=f2b(a.w);
  o[4]=f2b(b.x); o[5]=f2b(b.y); o[6]=f2b(b.z); o[7]=f2b(b.w);
  *(u16x8*)(out + (long)i * 8) = o;
}

// ---------------- transpose + cvt: W[K][N] f32 -> Wt[N][K] bf16 ----------------
__global__ __launch_bounds__(256) void transpose_cvt_kernel(
    const float* __restrict__ W, u16* __restrict__ Wt, int K, int N) {
  __shared__ float tile[32][33];   // +1 pad: no bank conflicts
  int tx = threadIdx.x & 31, ty = threadIdx.x >> 5; // 32x8
  int bx = blockIdx.x, by = blockIdx.y;
  #pragma unroll
  for (int r = 0; r < 32; r += 8)
    tile[ty + r][tx] = W[(long)(by * 32 + ty + r) * N + bx * 32 + tx];
  __syncthreads();
  #pragma unroll
  for (int r = 0; r < 32; r += 8)
    Wt[(long)(bx * 32 + ty + r) * K + by * 32 + tx] = f2b(tile[tx][ty + r]);
}

// ---------------- 128x128 bf16 GEMM, B given transposed [N][K] ----------------
// MODE 0: C[M][N] fp32 plain store.
// MODE 1: qkv scatter epilogue: col c = s*1024 + h*64 + d
//   s=0 -> Qb[bh][t][d] * 0.125   s=1 -> Kb[bh][t][d]   s=2 -> Vt[bh][d][t]
template<int MODE>
__global__ __launch_bounds__(256) void gemm_bt_kernel(
    const u16* __restrict__ A, const u16* __restrict__ Bt,
    float* __restrict__ C,
    u16* __restrict__ Qb, u16* __restrict__ Kb, u16* __restrict__ Vt,
    int M, int N, int K) {
  __shared__ u16 lA[128 * 32];
  __shared__ u16 lB[128 * 32];
  const int tid = threadIdx.x;
  const int l = tid & 63, w = tid >> 6;
  const int g = l >> 4, c16 = l & 15;
  const int bn = blockIdx.x, bm = blockIdx.y;
  const int wm = w >> 1, wn = w & 1;
  // staging: each thread stages 16B per issue; 2 issues per tile per operand
  const int srow = tid >> 2;
  const int scol = (tid & 3) << 3;
  const u16* Ab0 = A  + (long)(bm * 128 + srow)      * K + scol;
  const u16* Ab1 = A  + (long)(bm * 128 + 64 + srow) * K + scol;
  const u16* Bb0 = Bt + (long)(bn * 128 + srow)      * K + scol;
  const u16* Bb1 = Bt + (long)(bn * 128 + 64 + srow) * K + scol;
  u16* lA0 = &lA[srow * 32 + scol];
  u16* lA1 = &lA[(64 + srow) * 32 + scol];
  u16* lB0 = &lB[srow * 32 + scol];
  u16* lB1 = &lB[(64 + srow) * 32 + scol];

  f32x4 acc[4][4];
  #pragma unroll
  for (int i = 0; i < 4; ++i)
    #pragma unroll
    for (int j = 0; j < 4; ++j)
      #pragma unroll
      for (int e = 0; e < 4; ++e) acc[i][j][e] = 0.f;

  for (int k0 = 0; k0 < K; k0 += 32) {
    gload_lds16(Ab0 + k0, lA0);
    gload_lds16(Ab1 + k0, lA1);
    gload_lds16(Bb0 + k0, lB0);
    gload_lds16(Bb1 + k0, lB1);
    __syncthreads();   // drains vmcnt(0), LDS tile ready
    bf16x8 af[4];
    #pragma unroll
    for (int mf = 0; mf < 4; ++mf)
      af[mf] = *(const bf16x8*)&lA[(wm * 64 + mf * 16 + c16) * 32 + g * 8];
    #pragma unroll
    for (int nf = 0; nf < 4; ++nf) {
      bf16x8 bfr = *(const bf16x8*)&lB[(wn * 64 + nf * 16 + c16) * 32 + g * 8];
      #pragma unroll
      for (int mf = 0; mf < 4; ++mf)
        acc[mf][nf] = MFMA16(af[mf], bfr, acc[mf][nf]);
    }
    __syncthreads();   // protect LDS before next stage
  }

  #pragma unroll
  for (int mf = 0; mf < 4; ++mf) {
    const int trow_base = bm * 128 + wm * 64 + mf * 16 + g * 4;
    #pragma unroll
    for (int nf = 0; nf < 4; ++nf) {
      const int col = bn * 128 + wn * 64 + nf * 16 + c16;
      #pragma unroll
      for (int r = 0; r < 4; ++r) {
        const float v = acc[mf][nf][r];
        const int trow = trow_base + r;
        if constexpr (MODE == 0) {
          C[(long)trow * N + col] = v;
        } else {
          const int s = col >> 10;
          const int rem = col & 1023;
          const int h = rem >> 6, d = rem & 63;
          const int b = trow >> 11, tt = trow & 2047;
          const int bh = b * NHEADS + h;
          if (s == 0)      Qb[((long)bh * SEQ + tt) * DHEAD + d] = f2b(v * 0.125f);
          else if (s == 1) Kb[((long)bh * SEQ + tt) * DHEAD + d] = f2b(v);
          else             Vt[((long)bh * DHEAD + d) * SEQ + tt] = f2b(v);
        }
      }
    }
  }
}

// ---------------- causal flash attention ----------------
// grid (B*H, 16): block processes q-tiles (y) and (31-y)  -> constant 17 KV
// tiles of 128 keys each (load-balanced). 256 threads = 4 waves; wave wid owns
// 16 q-rows of the current q-tile. Q pre-scaled by 1/8. K [bh][t][64],
// Vt [bh][64][t], out Ob [b*T+t][h*64+d] bf16.
__global__ __launch_bounds__(256) void attn_kernel(
    const u16* __restrict__ Qb, const u16* __restrict__ Kb,
    const u16* __restrict__ Vt, u16* __restrict__ Ob) {
  __shared__ u16 lP[4][16 * 128];   // per-wave P buffer (4KB), XOR-swizzled
  const int tid = threadIdx.x;
  const int l = tid & 63, wid = tid >> 6;
  const int g = l >> 4, c16 = l & 15;
  const int bh = blockIdx.x;
  const int b = bh >> 4, h = bh & 15;
  const u16* Kbh = Kb + (long)bh * SEQ * DHEAD;
  const u16* Vbh = Vt + (long)bh * DHEAD * SEQ;

  #pragma unroll 1
  for (int pass = 0; pass < 2; ++pass) {
    const int qtile = (pass == 0) ? (int)blockIdx.y : (31 - (int)blockIdx.y);
    const int qb0 = qtile * 64;
    const int qrow = qb0 + wid * 16;

    // Q fragments (A-operand): row = qrow + c16, k-slice = ks*32 + 8g
    const u16* Qrow = &Qb[((long)bh * SEQ + qrow + c16) * DHEAD];
    bf16x8 aq0 = *(const bf16x8*)&Qrow[8 * g];
    bf16x8 aq1 = *(const bf16x8*)&Qrow[32 + 8 * g];

    f32x4 o[4];
    float m0[4], sumv[4];
    #pragma unroll
    for (int i = 0; i < 4; ++i) {
      #pragma unroll
      for (int e = 0; e < 4; ++e) o[i][e] = 0.f;
      m0[i] = -__builtin_inff(); sumv[i] = 0.f;
    }

    const int ntiles = qtile / 2 + 1;   // 128-key tiles covering 0..qb0+63
    for (int t = 0; t < ntiles; ++t) {
      const int kv = t * 128;
      // ---- S = Q K^T (per wave: 16 x 128) ----
      f32x4 s4[8];
      #pragma unroll
      for (int nf = 0; nf < 8; ++nf) {
        #pragma unroll
        for (int e = 0; e < 4; ++e) s4[nf][e] = 0.f;
        const u16* Krow = Kbh + (long)(kv + nf * 16 + c16) * DHEAD + 8 * g;
        bf16x8 bk0 = *(const bf16x8*)Krow;
        bf16x8 bk1 = *(const bf16x8*)(Krow + 32);
        s4[nf] = MFMA16(aq0, bk0, s4[nf]);
        s4[nf] = MFMA16(aq1, bk1, s4[nf]);
      }
      // ---- causal mask + per-row max (rows 4g+r, cols c16+16nf) ----
      float rmax[4];
      #pragma unroll
      for (int r = 0; r < 4; ++r) {
        const int q = qrow + 4 * g + r;
        float mx = -__builtin_inff();
        #pragma unroll
        for (int nf = 0; nf < 8; ++nf) {
          const int j = kv + nf * 16 + c16;
          float v = (j <= q) ? s4[nf][r] : -__builtin_inff();
          s4[nf][r] = v;
          mx = fmaxf(mx, v);
        }
        rmax[r] = mx;
      }
      #pragma unroll
      for (int mk = 1; mk < 16; mk <<= 1)
        #pragma unroll
        for (int r = 0; r < 4; ++r)
          rmax[r] = fmaxf(rmax[r], __shfl_xor(rmax[r], mk, 64));
      // ---- online softmax ----
      float fs[4], psum[4];
      #pragma unroll
      for (int r = 0; r < 4; ++r) {
        const float mnew = fmaxf(m0[r], rmax[r]);
        fs[r] = exp2f((m0[r] - mnew) * 1.44269504f);
        m0[r] = mnew;
        float ps = 0.f;
        #pragma unroll
        for (int nf = 0; nf < 8; ++nf) {
          const float p = exp2f((s4[nf][r] - mnew) * 1.44269504f);
          s4[nf][r] = p;
          ps += p;
        }
        psum[r] = ps;
      }
      #pragma unroll
      for (int mk = 1; mk < 16; mk <<= 1)
        #pragma unroll
        for (int r = 0; r < 4; ++r)
          psum[r] += __shfl_xor(psum[r], mk, 64);
      #pragma unroll
      for (int r = 0; r < 4; ++r) sumv[r] = sumv[r] * fs[r] + psum[r];
      #pragma unroll
      for (int df = 0; df < 4; ++df)
        #pragma unroll
        for (int r = 0; r < 4; ++r) o[df][r] *= fs[r];
      // ---- P -> LDS (bf16, row stride 256B, XOR swizzle byte ^= (row&7)<<4) ----
      #pragma unroll
      for (int r = 0; r < 4; ++r) {
        const int row = 4 * g + r;
        char* base = (char*)&lP[wid][0] + row * 256;
        #pragma unroll
        for (int nf = 0; nf < 8; ++nf) {
          const int off = (2 * (c16 + 16 * nf)) ^ ((row & 7) << 4);
          *(u16*)(base + off) = f2b(s4[nf][r]);
        }
      }
      asm volatile("" ::: "memory");   // order LDS writes before reads (same wave)
      // ---- P A-fragments: row = c16, k-slice = ks*32 + 8g ----
      bf16x8 ap[4];
      {
        const char* base = (const char*)&lP[wid][0] + c16 * 256;
        const int sw = (c16 & 7) << 4;
        #pragma unroll
        for (int ks = 0; ks < 4; ++ks)
          ap[ks] = *(const bf16x8*)(base + ((ks * 64 + 16 * g) ^ sw));
      }
      asm volatile("" ::: "memory");   // order LDS reads before next tile's writes
      // ---- O += P V ----
      #pragma unroll
      for (int df = 0; df < 4; ++df) {
        const u16* Vrow = Vbh + (long)(df * 16 + c16) * SEQ + kv + 8 * g;
        bf16x8 bv0 = *(const bf16x8*)Vrow;
        bf16x8 bv1 = *(const bf16x8*)(Vrow + 32);
        bf16x8 bv2 = *(const bf16x8*)(Vrow + 64);
        bf16x8 bv3 = *(const bf16x8*)(Vrow + 96);
        o[df] = MFMA16(ap[0], bv0, o[df]);
        o[df] = MFMA16(ap[1], bv1, o[df]);
        o[df] = MFMA16(ap[2], bv2, o[df]);
        o[df] = MFMA16(ap[3], bv3, o[df]);
      }
    }
    // ---- normalize + store [b*T+t][h*64 + d] bf16 ----
    #pragma unroll
    for (int df = 0; df < 4; ++df)
      #pragma unroll
      for (int r = 0; r < 4; ++r) {
        const float v = o[df][r] / sumv[r];
        const int trow = qrow + 4 * g + r;
        Ob[((long)b * SEQ + trow) * DMODEL + h * DHEAD + df * 16 + c16] = f2b(v);
      }
  }
}

extern "C" void kernel_launch(void* const* d_in, const int* in_sizes, int n_in,
                              void* d_out, int out_size, void* d_ws, size_t ws_size,
                              hipStream_t stream) {
  const float* x    = (const float*)d_in[0];
  // d_in[1] = mask (causal tril) — implemented implicitly
  const float* Wqkv = (const float*)d_in[2];
  const float* Wout = (const float*)d_in[3];
  float* out = (float*)d_out;
  char* ws = (char*)d_ws;
  // ws layout (bytes)
  u16* Xb  = (u16*)(ws + 0);          // 8192x1024 bf16      16,777,216
  u16* Wt1 = (u16*)(ws + 16777216);   // 3072x1024 bf16       6,291,456
  u16* Wt2 = (u16*)(ws + 23068672);   // 1024x1024 bf16       2,097,152
  u16* Qb  = (u16*)(ws + 25165824);   // [64][2048][64] bf16 16,777,216
  u16* Kb  = (u16*)(ws + 41943040);   // [64][2048][64] bf16 16,777,216
  u16* Vt  = (u16*)(ws + 58720256);   // [64][64][2048] bf16 16,777,216
  u16* Ob  = (u16*)(ws + 75497472);   // 8192x1024 bf16      16,777,216

  cvt_bf16_kernel<<<4096, 256, 0, stream>>>(x, Xb, BT * DMODEL / 8);
  transpose_cvt_kernel<<<dim3(96, 32), 256, 0, stream>>>(Wqkv, Wt1, DMODEL, 3 * DMODEL);
  transpose_cvt_kernel<<<dim3(32, 32), 256, 0, stream>>>(Wout, Wt2, DMODEL, DMODEL);
  gemm_bt_kernel<1><<<dim3(24, 64), 256, 0, stream>>>(
      Xb, Wt1, nullptr, Qb, Kb, Vt, BT, 3 * DMODEL, DMODEL);
  attn_kernel<<<dim3(64, 16), 256, 0, stream>>>(Qb, Kb, Vt, Ob);
  gemm_bt_kernel<0><<<dim3(8, 64), 256, 0, stream>>>(
      Ob, Wt2, out, nullptr, nullptr, nullptr, BT, DMODEL, DMODEL);
}

// Round 10
// 304.587 us; speedup vs baseline: 1.7586x; 1.7586x over previous
//
#include <hip/hip_runtime.h>
#include <hip/hip_bf16.h>

// Problem constants
#define BATCH   4
#define SEQ     2048
#define DMODEL  1024
#define NHEADS  16
#define DHEAD   64
#define BT      (BATCH*SEQ)   // 8192 tokens

typedef unsigned short u16;
typedef unsigned int u32;
typedef __bf16 bf16x8 __attribute__((ext_vector_type(8)));
typedef float  f32x4  __attribute__((ext_vector_type(4)));
typedef float  f32x16 __attribute__((ext_vector_type(16)));
typedef u16    u16x8  __attribute__((ext_vector_type(8)));
typedef u16    u16x4  __attribute__((ext_vector_type(4)));
typedef u32    u32x4  __attribute__((ext_vector_type(4)));

#define MFMA16(a,b,c) __builtin_amdgcn_mfma_f32_16x16x32_bf16((a),(b),(c),0,0,0)
#define MFMA32(a,b,c) __builtin_amdgcn_mfma_f32_32x32x16_bf16((a),(b),(c),0,0,0)

__device__ __forceinline__ u16 f2b(float f) {
  return __builtin_bit_cast(u16, (__bf16)f);
}
__device__ __forceinline__ u32 pack2(float lo, float hi) {
  return (u32)f2b(lo) | ((u32)f2b(hi) << 16);
}

__device__ __forceinline__ void gload_lds16(const u16* g, u16* l) {
  __builtin_amdgcn_global_load_lds(
      (const __attribute__((address_space(1))) void*)g,
      (__attribute__((address_space(3))) void*)l, 16, 0, 0);
}

// ---------------- elementwise f32 -> bf16 ----------------
__global__ __launch_bounds__(256) void cvt_bf16_kernel(
    const float* __restrict__ in, u16* __restrict__ out, int n8) {
  int i = blockIdx.x * 256 + threadIdx.x;
  if (i >= n8) return;
  const float4* p = (const float4*)(in + (long)i * 8);
  float4 a = p[0], b = p[1];
  u16x8 o;
  o[0]=f2b(a.x); o[1]=f2b(a.y); o[2]=f2b(a.z); o[3]=f2b(a.w);
  o[4]=f2b(b.x); o[5]=f2b(b.y); o[6]=f2b(b.z); o[7]=f2b(b.w);
  *(u16x8*)(out + (long)i * 8) = o;
}

// ---------------- transpose + cvt: W[K][N] f32 -> Wt[N][K] bf16 ----------------
__global__ __launch_bounds__(256) void transpose_cvt_kernel(
    const float* __restrict__ W, u16* __restrict__ Wt, int K, int N) {
  __shared__ float tile[32][33];   // +1 pad: no bank conflicts
  int tx = threadIdx.x & 31, ty = threadIdx.x >> 5; // 32x8
  int bx = blockIdx.x, by = blockIdx.y;
  #pragma unroll
  for (int r = 0; r < 32; r += 8)
    tile[ty + r][tx] = W[(long)(by * 32 + ty + r) * N + bx * 32 + tx];
  __syncthreads();
  #pragma unroll
  for (int r = 0; r < 32; r += 8)
    Wt[(long)(bx * 32 + ty + r) * K + by * 32 + tx] = f2b(tile[tx][ty + r]);
}

// ---------------- 128x128 bf16 GEMM, B given transposed [N][K] ----------------
// MODE 0: C[M][N] fp32 plain store.
// MODE 1: qkv scatter epilogue: col c = s*1024 + h*64 + d
//   s=0 -> Qb[bh][t][d] * 0.125   s=1 -> Kb[bh][t][d]   s=2 -> Vt[bh][d][t]
template<int MODE>
__global__ __launch_bounds__(256) void gemm_bt_kernel(
    const u16* __restrict__ A, const u16* __restrict__ Bt,
    float* __restrict__ C,
    u16* __restrict__ Qb, u16* __restrict__ Kb, u16* __restrict__ Vt,
    int M, int N, int K) {
  __shared__ u16 lA[128 * 32];
  __shared__ u16 lB[128 * 32];
  const int tid = threadIdx.x;
  const int l = tid & 63, w = tid >> 6;
  const int g = l >> 4, c16 = l & 15;
  const int bn = blockIdx.x, bm = blockIdx.y;
  const int wm = w >> 1, wn = w & 1;
  const int srow = tid >> 2;
  const int scol = (tid & 3) << 3;
  const u16* Ab0 = A  + (long)(bm * 128 + srow)      * K + scol;
  const u16* Ab1 = A  + (long)(bm * 128 + 64 + srow) * K + scol;
  const u16* Bb0 = Bt + (long)(bn * 128 + srow)      * K + scol;
  const u16* Bb1 = Bt + (long)(bn * 128 + 64 + srow) * K + scol;
  u16* lA0 = &lA[srow * 32 + scol];
  u16* lA1 = &lA[(64 + srow) * 32 + scol];
  u16* lB0 = &lB[srow * 32 + scol];
  u16* lB1 = &lB[(64 + srow) * 32 + scol];

  f32x4 acc[4][4];
  #pragma unroll
  for (int i = 0; i < 4; ++i)
    #pragma unroll
    for (int j = 0; j < 4; ++j)
      #pragma unroll
      for (int e = 0; e < 4; ++e) acc[i][j][e] = 0.f;

  for (int k0 = 0; k0 < K; k0 += 32) {
    gload_lds16(Ab0 + k0, lA0);
    gload_lds16(Ab1 + k0, lA1);
    gload_lds16(Bb0 + k0, lB0);
    gload_lds16(Bb1 + k0, lB1);
    __syncthreads();
    bf16x8 af[4];
    #pragma unroll
    for (int mf = 0; mf < 4; ++mf)
      af[mf] = *(const bf16x8*)&lA[(wm * 64 + mf * 16 + c16) * 32 + g * 8];
    #pragma unroll
    for (int nf = 0; nf < 4; ++nf) {
      bf16x8 bfr = *(const bf16x8*)&lB[(wn * 64 + nf * 16 + c16) * 32 + g * 8];
      #pragma unroll
      for (int mf = 0; mf < 4; ++mf)
        acc[mf][nf] = MFMA16(af[mf], bfr, acc[mf][nf]);
    }
    __syncthreads();
  }

  #pragma unroll
  for (int mf = 0; mf < 4; ++mf) {
    const int trow_base = bm * 128 + wm * 64 + mf * 16 + g * 4;
    #pragma unroll
    for (int nf = 0; nf < 4; ++nf) {
      const int col = bn * 128 + wn * 64 + nf * 16 + c16;
      #pragma unroll
      for (int r = 0; r < 4; ++r) {
        const float v = acc[mf][nf][r];
        const int trow = trow_base + r;
        if constexpr (MODE == 0) {
          C[(long)trow * N + col] = v;
        } else {
          const int s = col >> 10;
          const int rem = col & 1023;
          const int h = rem >> 6, d = rem & 63;
          const int b = trow >> 11, tt = trow & 2047;
          const int bh = b * NHEADS + h;
          if (s == 0)      Qb[((long)bh * SEQ + tt) * DHEAD + d] = f2b(v * 0.125f);
          else if (s == 1) Kb[((long)bh * SEQ + tt) * DHEAD + d] = f2b(v);
          else             Vt[((long)bh * DHEAD + d) * SEQ + tt] = f2b(v);
        }
      }
    }
  }
}

// ---------------- causal flash attention, 8-wave swapped-QK^T ----------------
// grid (64 bh, 4). Block (512 thr = 8 waves) processes q-blocks y*256 and
// (7-y)*256 -> constant 36 KV tiles of 64 keys. Wave w owns 32 q-rows.
// S^T = K*Q^T via mfma_32x32x16 so each lane holds 32 keys for ONE q
// (in-lane softmax + 1 shfl_xor(32)). K/V tiles cooperatively staged in LDS
// (double-buffered, XOR-swizzled source, counted vmcnt). P repacked to bf16
// B-operand in registers. Q pre-scaled by 1/8.
// K [bh][t][64], Vt [bh][64][t], out Ob [b*T+t][h*64+d] bf16.
__global__ __launch_bounds__(512, 2) void attn_kernel(
    const u16* __restrict__ Qb, const u16* __restrict__ Kb,
    const u16* __restrict__ Vt, u16* __restrict__ Ob) {
  __shared__ u16 kbuf[2][64 * 64];   // [key][d], rows 128B, XOR-swizzled
  __shared__ u16 vbuf[2][64 * 64];   // [d][key], rows 128B, XOR-swizzled
  const int tid = threadIdx.x;
  const int lane = tid & 63, w = tid >> 6;
  const int c = lane & 31, g2 = lane >> 5;
  const int bh = blockIdx.x;
  const int b = bh >> 4, h = bh & 15;
  const u16* Kbh = Kb + (long)bh * SEQ * DHEAD;
  const u16* Vbh = Vt + (long)bh * DHEAD * SEQ;

  // staging geometry: wave w stages rows w*8..w*8+7 of each tile (1KB issue)
  const int srow = lane >> 3;              // row within 8-row group
  const int sswz = ((lane & 7) * 16) ^ (srow << 4);   // bytes, pre-swizzled src
  const int swz  = (c & 7) << 4;           // read-side XOR (row&7 == c&7)

  #pragma unroll 1
  for (int pass = 0; pass < 2; ++pass) {
    const int qblk = pass ? (7 - (int)blockIdx.y) : (int)blockIdx.y;
    const int qb0 = qblk * 256;
    const int qrow0 = qb0 + w * 32;
    const int nt = qb0 / 64 + 4;           // tiles staged by the block
    const int mytiles = (qrow0 + 31) / 64 + 1;  // tiles this wave computes

    // Q fragments (B-operand): B[kk][j=c] = Q[qrow0+c][ds*16 + g2*8 + idx]
    bf16x8 qf[4];
    {
      const u16* Qrow = Qb + ((long)bh * SEQ + qrow0 + c) * DHEAD + g2 * 8;
      #pragma unroll
      for (int ds = 0; ds < 4; ++ds)
        qf[ds] = *(const bf16x8*)(Qrow + ds * 16);
    }

    f32x16 o0, o1;               // O^T accum: rows d (+0/+32), col q
    #pragma unroll
    for (int e = 0; e < 16; ++e) { o0[e] = 0.f; o1[e] = 0.f; }
    float m_run = -__builtin_inff(), l_run = 0.f;

    // prologue: stage tile 0
    {
      const u16* gk = Kbh + (long)(w * 8 + srow) * DHEAD + (sswz >> 1);
      gload_lds16(gk, &kbuf[0][w * 512]);
      const u16* gv = Vbh + (long)(w * 8 + srow) * SEQ + (sswz >> 1);
      gload_lds16(gv, &vbuf[0][w * 512]);
    }
    asm volatile("s_waitcnt vmcnt(0)" ::: "memory");
    __builtin_amdgcn_s_barrier();

    #pragma unroll 1
    for (int t = 0; t < nt; ++t) {
      const int kv = t * 64;
      const int cur = t & 1;
      if (t + 1 < nt) {
        const int kv2 = kv + 64;
        const u16* gk = Kbh + (long)(kv2 + w * 8 + srow) * DHEAD + (sswz >> 1);
        gload_lds16(gk, &kbuf[cur ^ 1][w * 512]);
        const u16* gv = Vbh + (long)(w * 8 + srow) * SEQ + kv2 + (sswz >> 1);
        gload_lds16(gv, &vbuf[cur ^ 1][w * 512]);
        asm volatile("s_waitcnt vmcnt(2)" ::: "memory");   // tile t complete
      } else {
        asm volatile("s_waitcnt vmcnt(0)" ::: "memory");
      }
      __builtin_amdgcn_s_barrier();

      if (t < mytiles) {
        // ---- S^T = K * Q^T : p0 keys kv..+31, p1 keys kv+32..+63 ----
        f32x16 p0, p1;
        #pragma unroll
        for (int e = 0; e < 16; ++e) { p0[e] = 0.f; p1[e] = 0.f; }
        const char* kb = (const char*)&kbuf[cur][0];
        __builtin_amdgcn_s_setprio(1);
        #pragma unroll
        for (int ds = 0; ds < 4; ++ds) {
          bf16x8 aK0 = *(const bf16x8*)(kb + c * 128 + ((ds * 32 + g2 * 16) ^ swz));
          bf16x8 aK1 = *(const bf16x8*)(kb + (32 + c) * 128 + ((ds * 32 + g2 * 16) ^ swz));
          p0 = MFMA32(aK0, qf[ds], p0);
          p1 = MFMA32(aK1, qf[ds], p1);
        }
        __builtin_amdgcn_s_setprio(0);

        // ---- causal mask: needed iff any key in tile can exceed the wave's
        // MIN q (qrow0).  (v7 bug: compared against qrow0+31, skipping the
        // boundary tile of odd waves -> future-key leakage.) ----
        if (kv + 63 > qrow0) {
          const int q = qrow0 + c;
          #pragma unroll
          for (int r = 0; r < 16; ++r) {
            const int koff = (r & 3) + 8 * (r >> 2) + 4 * g2;
            if (kv + koff > q)      p0[r] = -__builtin_inff();
            if (kv + 32 + koff > q) p1[r] = -__builtin_inff();
          }
        }

        // ---- online softmax (in-lane over 32 keys + 1 half-swap) ----
        float vmax = p0[0];
        #pragma unroll
        for (int e = 1; e < 16; ++e) vmax = fmaxf(vmax, p0[e]);
        #pragma unroll
        for (int e = 0; e < 16; ++e) vmax = fmaxf(vmax, p1[e]);
        vmax = fmaxf(vmax, __shfl_xor(vmax, 32, 64));
        const float mnew = fmaxf(m_run, vmax);
        const float scale = __builtin_amdgcn_exp2f((m_run - mnew) * 1.44269504f);
        m_run = mnew;
        float ps = 0.f;
        #pragma unroll
        for (int e = 0; e < 16; ++e) {
          p0[e] = __builtin_amdgcn_exp2f((p0[e] - mnew) * 1.44269504f);
          p1[e] = __builtin_amdgcn_exp2f((p1[e] - mnew) * 1.44269504f);
          ps += p0[e] + p1[e];
        }
        ps += __shfl_xor(ps, 32, 64);
        l_run = l_run * scale + ps;
        #pragma unroll
        for (int e = 0; e < 16; ++e) { o0[e] *= scale; o1[e] *= scale; }

        // ---- repack P -> bf16 B-operand frags pbw[s] (16 keys each) ----
        u32x4 pbw[4];
        #pragma unroll
        for (int s = 0; s < 4; ++s) {
          const int base = 8 * (s & 1);
          float e0, e1, e2, e3, e4, e5, e6, e7;
          if (s < 2) {
            e0=p0[base+0]; e1=p0[base+1]; e2=p0[base+2]; e3=p0[base+3];
            e4=p0[base+4]; e5=p0[base+5]; e6=p0[base+6]; e7=p0[base+7];
          } else {
            e0=p1[base+0]; e1=p1[base+1]; e2=p1[base+2]; e3=p1[base+3];
            e4=p1[base+4]; e5=p1[base+5]; e6=p1[base+6]; e7=p1[base+7];
          }
          const u32 w01 = pack2(e0, e1), w23 = pack2(e2, e3);
          const u32 w45 = pack2(e4, e5), w67 = pack2(e6, e7);
          // send the words destined for the partner half, receive ours
          const u32 sendA = g2 ? w01 : w45;
          const u32 sendB = g2 ? w23 : w67;
          const u32 recvA = (u32)__shfl_xor((int)sendA, 32, 64);
          const u32 recvB = (u32)__shfl_xor((int)sendB, 32, 64);
          pbw[s][0] = g2 ? recvA : w01;
          pbw[s][1] = g2 ? recvB : w23;
          pbw[s][2] = g2 ? w45 : recvA;
          pbw[s][3] = g2 ? w67 : recvB;
        }

        // ---- O^T += V^T * P^T ----
        const char* vb = (const char*)&vbuf[cur][0];
        __builtin_amdgcn_s_setprio(1);
        #pragma unroll
        for (int s = 0; s < 4; ++s) {
          const bf16x8 pv = __builtin_bit_cast(bf16x8, pbw[s]);
          bf16x8 aV0 = *(const bf16x8*)(vb + c * 128 + ((s * 32 + g2 * 16) ^ swz));
          bf16x8 aV1 = *(const bf16x8*)(vb + (32 + c) * 128 + ((s * 32 + g2 * 16) ^ swz));
          o0 = MFMA32(aV0, pv, o0);
          o1 = MFMA32(aV1, pv, o1);
        }
        __builtin_amdgcn_s_setprio(0);
      }
      asm volatile("" ::: "memory");
      __builtin_amdgcn_s_barrier();
    }

    // ---- normalize + store [b*T+q][h*64 + d] ----
    const float rinv = 1.f / l_run;
    const int q = qrow0 + c;
    u16* orow = Ob + ((long)b * SEQ + q) * DMODEL + h * DHEAD;
    #pragma unroll
    for (int m = 0; m < 4; ++m) {
      u16x4 v0, v1;
      #pragma unroll
      for (int e = 0; e < 4; ++e) {
        v0[e] = f2b(o0[4 * m + e] * rinv);
        v1[e] = f2b(o1[4 * m + e] * rinv);
      }
      const int d0 = 8 * m + 4 * g2;
      *(u16x4*)(orow + d0) = v0;
      *(u16x4*)(orow + 32 + d0) = v1;
    }
  }
}

extern "C" void kernel_launch(void* const* d_in, const int* in_sizes, int n_in,
                              void* d_out, int out_size, void* d_ws, size_t ws_size,
                              hipStream_t stream) {
  const float* x    = (const float*)d_in[0];
  // d_in[1] = mask (causal tril) — implemented implicitly
  const float* Wqkv = (const float*)d_in[2];
  const float* Wout = (const float*)d_in[3];
  float* out = (float*)d_out;
  char* ws = (char*)d_ws;
  u16* Xb  = (u16*)(ws + 0);          // 8192x1024 bf16      16,777,216
  u16* Wt1 = (u16*)(ws + 16777216);   // 3072x1024 bf16       6,291,456
  u16* Wt2 = (u16*)(ws + 23068672);   // 1024x1024 bf16       2,097,152
  u16* Qb  = (u16*)(ws + 25165824);   // [64][2048][64] bf16 16,777,216
  u16* Kb  = (u16*)(ws + 41943040);   // [64][2048][64] bf16 16,777,216
  u16* Vt  = (u16*)(ws + 58720256);   // [64][64][2048] bf16 16,777,216
  u16* Ob  = (u16*)(ws + 75497472);   // 8192x1024 bf16      16,777,216

  cvt_bf16_kernel<<<4096, 256, 0, stream>>>(x, Xb, BT * DMODEL / 8);
  transpose_cvt_kernel<<<dim3(96, 32), 256, 0, stream>>>(Wqkv, Wt1, DMODEL, 3 * DMODEL);
  transpose_cvt_kernel<<<dim3(32, 32), 256, 0, stream>>>(Wout, Wt2, DMODEL, DMODEL);
  gemm_bt_kernel<1><<<dim3(24, 64), 256, 0, stream>>>(
      Xb, Wt1, nullptr, Qb, Kb, Vt, BT, 3 * DMODEL, DMODEL);
  attn_kernel<<<dim3(64, 4), 512, 0, stream>>>(Qb, Kb, Vt, Ob);
  gemm_bt_kernel<0><<<dim3(8, 64), 256, 0, stream>>>(
      Ob, Wt2, out, nullptr, nullptr, nullptr, BT, DMODEL, DMODEL);
}

// Round 11
// 296.840 us; speedup vs baseline: 1.8045x; 1.0261x over previous
//
#include <hip/hip_runtime.h>
#include <hip/hip_bf16.h>

// Problem constants
#define BATCH   4
#define SEQ     2048
#define DMODEL  1024
#define NHEADS  16
#define DHEAD   64
#define BT      (BATCH*SEQ)   // 8192 tokens

typedef unsigned short u16;
typedef unsigned int u32;
typedef __bf16 bf16x8 __attribute__((ext_vector_type(8)));
typedef float  f32x4  __attribute__((ext_vector_type(4)));
typedef float  f32x16 __attribute__((ext_vector_type(16)));
typedef u16    u16x8  __attribute__((ext_vector_type(8)));
typedef u16    u16x4  __attribute__((ext_vector_type(4)));
typedef u32    u32x4  __attribute__((ext_vector_type(4)));

#define MFMA16(a,b,c) __builtin_amdgcn_mfma_f32_16x16x32_bf16((a),(b),(c),0,0,0)
#define MFMA32(a,b,c) __builtin_amdgcn_mfma_f32_32x32x16_bf16((a),(b),(c),0,0,0)

__device__ __forceinline__ u16 f2b(float f) {
  return __builtin_bit_cast(u16, (__bf16)f);
}
__device__ __forceinline__ u32 pack2(float lo, float hi) {
  return (u32)f2b(lo) | ((u32)f2b(hi) << 16);
}

__device__ __forceinline__ void gload_lds16(const u16* g, u16* l) {
  __builtin_amdgcn_global_load_lds(
      (const __attribute__((address_space(1))) void*)g,
      (__attribute__((address_space(3))) void*)l, 16, 0, 0);
}

// ---------------- elementwise f32 -> bf16 ----------------
__global__ __launch_bounds__(256) void cvt_bf16_kernel(
    const float* __restrict__ in, u16* __restrict__ out, int n8) {
  int i = blockIdx.x * 256 + threadIdx.x;
  if (i >= n8) return;
  const float4* p = (const float4*)(in + (long)i * 8);
  float4 a = p[0], b = p[1];
  u16x8 o;
  o[0]=f2b(a.x); o[1]=f2b(a.y); o[2]=f2b(a.z); o[3]=f2b(a.w);
  o[4]=f2b(b.x); o[5]=f2b(b.y); o[6]=f2b(b.z); o[7]=f2b(b.w);
  *(u16x8*)(out + (long)i * 8) = o;
}

// ---------------- transpose + cvt: W[K][N] f32 -> Wt[N][K] bf16 ----------------
__global__ __launch_bounds__(256) void transpose_cvt_kernel(
    const float* __restrict__ W, u16* __restrict__ Wt, int K, int N) {
  __shared__ float tile[32][33];   // +1 pad: no bank conflicts
  int tx = threadIdx.x & 31, ty = threadIdx.x >> 5; // 32x8
  int bx = blockIdx.x, by = blockIdx.y;
  #pragma unroll
  for (int r = 0; r < 32; r += 8)
    tile[ty + r][tx] = W[(long)(by * 32 + ty + r) * N + bx * 32 + tx];
  __syncthreads();
  #pragma unroll
  for (int r = 0; r < 32; r += 8)
    Wt[(long)(bx * 32 + ty + r) * K + by * 32 + tx] = f2b(tile[tx][ty + r]);
}

// ---------------- 128x128 bf16 GEMM, B given transposed [N][K] ----------------
// BK=64, double-buffered LDS, counted vmcnt (stage t+1 before compute t),
// XOR-swizzled LDS (byte ^= (row&7)<<4, pre-swizzled global source).
// MODE 0: C[M][N] fp32 plain store.
// MODE 1: qkv scatter epilogue: col c = s*1024 + h*64 + d
//   s=0 -> Qb[bh][t][d] * 0.125   s=1 -> Kb[bh][t][d]   s=2 -> Vt[bh][d][t]
template<int MODE>
__global__ __launch_bounds__(256) void gemm_bt_kernel(
    const u16* __restrict__ A, const u16* __restrict__ Bt,
    float* __restrict__ C,
    u16* __restrict__ Qb, u16* __restrict__ Kb, u16* __restrict__ Vt,
    int M, int N, int K) {
  __shared__ u16 lA[2][128 * 64];   // [buf][row*64 + col], rows 128B
  __shared__ u16 lB[2][128 * 64];
  const int tid = threadIdx.x;
  const int l = tid & 63, w = tid >> 6;
  const int g = l >> 4, c16 = l & 15;
  const int bn = blockIdx.x, bm = blockIdx.y;
  const int wm = w >> 1, wn = w & 1;
  // staging: thread stages 16B of row (tid>>3)+32h, LDS slot tid&7;
  // source column pre-swizzled so read-side XOR finds linear k.
  const int srow = tid >> 3;               // 0..31
  const int sslot = tid & 7;
  const int scol = ((sslot ^ (srow & 7)) << 3);   // u16 units
  const u16* Ab = A  + (long)(bm * 128 + srow) * K + scol;
  const u16* Bb = Bt + (long)(bn * 128 + srow) * K + scol;
  const int ldst = srow * 64 + sslot * 8;  // u16 units within a buffer

  f32x4 acc[4][4];
  #pragma unroll
  for (int i = 0; i < 4; ++i)
    #pragma unroll
    for (int j = 0; j < 4; ++j)
      #pragma unroll
      for (int e = 0; e < 4; ++e) acc[i][j][e] = 0.f;

  const int nt = K >> 6;
  // prologue: stage tile 0
  #pragma unroll
  for (int h = 0; h < 4; ++h) {
    gload_lds16(Ab + (long)h * 32 * K, &lA[0][h * 32 * 64 + ldst]);
    gload_lds16(Bb + (long)h * 32 * K, &lB[0][h * 32 * 64 + ldst]);
  }
  asm volatile("s_waitcnt vmcnt(0)" ::: "memory");
  __builtin_amdgcn_s_barrier();

  #pragma unroll 1
  for (int t = 0; t < nt; ++t) {
    const int cur = t & 1;
    if (t + 1 < nt) {
      const long koff = (long)(t + 1) * 64;
      #pragma unroll
      for (int h = 0; h < 4; ++h) {
        gload_lds16(Ab + (long)h * 32 * K + koff, &lA[cur ^ 1][h * 32 * 64 + ldst]);
        gload_lds16(Bb + (long)h * 32 * K + koff, &lB[cur ^ 1][h * 32 * 64 + ldst]);
      }
      asm volatile("s_waitcnt vmcnt(8)" ::: "memory");  // tile t landed; t+1 in flight
    } else {
      asm volatile("s_waitcnt vmcnt(0)" ::: "memory");
    }
    __builtin_amdgcn_s_barrier();
    asm volatile("" ::: "memory");

    const char* a0 = (const char*)&lA[cur][0];
    const char* b0 = (const char*)&lB[cur][0];
    const int swz = (c16 & 7) << 4;
    __builtin_amdgcn_s_setprio(1);
    #pragma unroll
    for (int ks = 0; ks < 2; ++ks) {
      bf16x8 af[4], bfr[4];
      #pragma unroll
      for (int mf = 0; mf < 4; ++mf)
        af[mf] = *(const bf16x8*)(a0 + (wm * 64 + mf * 16 + c16) * 128 +
                                  (((ks * 4 + g) * 16) ^ swz));
      #pragma unroll
      for (int nf = 0; nf < 4; ++nf)
        bfr[nf] = *(const bf16x8*)(b0 + (wn * 64 + nf * 16 + c16) * 128 +
                                   (((ks * 4 + g) * 16) ^ swz));
      #pragma unroll
      for (int nf = 0; nf < 4; ++nf)
        #pragma unroll
        for (int mf = 0; mf < 4; ++mf)
          acc[mf][nf] = MFMA16(af[mf], bfr[nf], acc[mf][nf]);
    }
    __builtin_amdgcn_s_setprio(0);
    asm volatile("" ::: "memory");
    __builtin_amdgcn_s_barrier();
  }

  #pragma unroll
  for (int mf = 0; mf < 4; ++mf) {
    const int trow_base = bm * 128 + wm * 64 + mf * 16 + g * 4;
    #pragma unroll
    for (int nf = 0; nf < 4; ++nf) {
      const int col = bn * 128 + wn * 64 + nf * 16 + c16;
      #pragma unroll
      for (int r = 0; r < 4; ++r) {
        const float v = acc[mf][nf][r];
        const int trow = trow_base + r;
        if constexpr (MODE == 0) {
          C[(long)trow * N + col] = v;
        } else {
          const int s = col >> 10;
          const int rem = col & 1023;
          const int h = rem >> 6, d = rem & 63;
          const int b = trow >> 11, tt = trow & 2047;
          const int bh = b * NHEADS + h;
          if (s == 0)      Qb[((long)bh * SEQ + tt) * DHEAD + d] = f2b(v * 0.125f);
          else if (s == 1) Kb[((long)bh * SEQ + tt) * DHEAD + d] = f2b(v);
          else             Vt[((long)bh * DHEAD + d) * SEQ + tt] = f2b(v);
        }
      }
    }
  }
}

// ---------------- causal flash attention, 8-wave swapped-QK^T ----------------
// grid (64 bh, 4). Block (512 thr = 8 waves) processes q-blocks y*256 and
// (7-y)*256 -> constant 36 KV tiles of 64 keys. Wave w owns 32 q-rows.
// S^T = K*Q^T via mfma_32x32x16 so each lane holds 32 keys for ONE q
// (in-lane softmax + 1 shfl_xor(32)). K/V tiles cooperatively staged in LDS
// (double-buffered, XOR-swizzled source, counted vmcnt). P repacked to bf16
// B-operand in registers. Q pre-scaled by 1/8.
// K [bh][t][64], Vt [bh][64][t], out Ob [b*T+t][h*64+d] bf16.
__global__ __launch_bounds__(512, 2) void attn_kernel(
    const u16* __restrict__ Qb, const u16* __restrict__ Kb,
    const u16* __restrict__ Vt, u16* __restrict__ Ob) {
  __shared__ u16 kbuf[2][64 * 64];   // [key][d], rows 128B, XOR-swizzled
  __shared__ u16 vbuf[2][64 * 64];   // [d][key], rows 128B, XOR-swizzled
  const int tid = threadIdx.x;
  const int lane = tid & 63, w = tid >> 6;
  const int c = lane & 31, g2 = lane >> 5;
  const int bh = blockIdx.x;
  const int b = bh >> 4, h = bh & 15;
  const u16* Kbh = Kb + (long)bh * SEQ * DHEAD;
  const u16* Vbh = Vt + (long)bh * DHEAD * SEQ;

  // staging geometry: wave w stages rows w*8..w*8+7 of each tile (1KB issue)
  const int srow = lane >> 3;              // row within 8-row group
  const int sswz = ((lane & 7) * 16) ^ (srow << 4);   // bytes, pre-swizzled src
  const int swz  = (c & 7) << 4;           // read-side XOR (row&7 == c&7)

  #pragma unroll 1
  for (int pass = 0; pass < 2; ++pass) {
    const int qblk = pass ? (7 - (int)blockIdx.y) : (int)blockIdx.y;
    const int qb0 = qblk * 256;
    const int qrow0 = qb0 + w * 32;
    const int nt = qb0 / 64 + 4;           // tiles staged by the block
    const int mytiles = (qrow0 + 31) / 64 + 1;  // tiles this wave computes

    // Q fragments (B-operand): B[kk][j=c] = Q[qrow0+c][ds*16 + g2*8 + idx]
    bf16x8 qf[4];
    {
      const u16* Qrow = Qb + ((long)bh * SEQ + qrow0 + c) * DHEAD + g2 * 8;
      #pragma unroll
      for (int ds = 0; ds < 4; ++ds)
        qf[ds] = *(const bf16x8*)(Qrow + ds * 16);
    }

    f32x16 o0, o1;               // O^T accum: rows d (+0/+32), col q
    #pragma unroll
    for (int e = 0; e < 16; ++e) { o0[e] = 0.f; o1[e] = 0.f; }
    float m_run = -__builtin_inff(), l_run = 0.f;

    // prologue: stage tile 0
    {
      const u16* gk = Kbh + (long)(w * 8 + srow) * DHEAD + (sswz >> 1);
      gload_lds16(gk, &kbuf[0][w * 512]);
      const u16* gv = Vbh + (long)(w * 8 + srow) * SEQ + (sswz >> 1);
      gload_lds16(gv, &vbuf[0][w * 512]);
    }
    asm volatile("s_waitcnt vmcnt(0)" ::: "memory");
    __builtin_amdgcn_s_barrier();

    #pragma unroll 1
    for (int t = 0; t < nt; ++t) {
      const int kv = t * 64;
      const int cur = t & 1;
      if (t + 1 < nt) {
        const int kv2 = kv + 64;
        const u16* gk = Kbh + (long)(kv2 + w * 8 + srow) * DHEAD + (sswz >> 1);
        gload_lds16(gk, &kbuf[cur ^ 1][w * 512]);
        const u16* gv = Vbh + (long)(w * 8 + srow) * SEQ + kv2 + (sswz >> 1);
        gload_lds16(gv, &vbuf[cur ^ 1][w * 512]);
        asm volatile("s_waitcnt vmcnt(2)" ::: "memory");   // tile t complete
      } else {
        asm volatile("s_waitcnt vmcnt(0)" ::: "memory");
      }
      __builtin_amdgcn_s_barrier();

      if (t < mytiles) {
        // ---- S^T = K * Q^T : p0 keys kv..+31, p1 keys kv+32..+63 ----
        f32x16 p0, p1;
        #pragma unroll
        for (int e = 0; e < 16; ++e) { p0[e] = 0.f; p1[e] = 0.f; }
        const char* kb = (const char*)&kbuf[cur][0];
        __builtin_amdgcn_s_setprio(1);
        #pragma unroll
        for (int ds = 0; ds < 4; ++ds) {
          bf16x8 aK0 = *(const bf16x8*)(kb + c * 128 + ((ds * 32 + g2 * 16) ^ swz));
          bf16x8 aK1 = *(const bf16x8*)(kb + (32 + c) * 128 + ((ds * 32 + g2 * 16) ^ swz));
          p0 = MFMA32(aK0, qf[ds], p0);
          p1 = MFMA32(aK1, qf[ds], p1);
        }
        __builtin_amdgcn_s_setprio(0);

        // ---- causal mask: needed iff any key in tile can exceed the wave's
        // MIN q (qrow0). ----
        if (kv + 63 > qrow0) {
          const int q = qrow0 + c;
          #pragma unroll
          for (int r = 0; r < 16; ++r) {
            const int koff = (r & 3) + 8 * (r >> 2) + 4 * g2;
            if (kv + koff > q)      p0[r] = -__builtin_inff();
            if (kv + 32 + koff > q) p1[r] = -__builtin_inff();
          }
        }

        // ---- online softmax (in-lane over 32 keys + 1 half-swap) ----
        float vmax = p0[0];
        #pragma unroll
        for (int e = 1; e < 16; ++e) vmax = fmaxf(vmax, p0[e]);
        #pragma unroll
        for (int e = 0; e < 16; ++e) vmax = fmaxf(vmax, p1[e]);
        vmax = fmaxf(vmax, __shfl_xor(vmax, 32, 64));
        const float mnew = fmaxf(m_run, vmax);
        const float scale = __builtin_amdgcn_exp2f((m_run - mnew) * 1.44269504f);
        m_run = mnew;
        float ps = 0.f;
        #pragma unroll
        for (int e = 0; e < 16; ++e) {
          p0[e] = __builtin_amdgcn_exp2f((p0[e] - mnew) * 1.44269504f);
          p1[e] = __builtin_amdgcn_exp2f((p1[e] - mnew) * 1.44269504f);
          ps += p0[e] + p1[e];
        }
        ps += __shfl_xor(ps, 32, 64);
        l_run = l_run * scale + ps;
        #pragma unroll
        for (int e = 0; e < 16; ++e) { o0[e] *= scale; o1[e] *= scale; }

        // ---- repack P -> bf16 B-operand frags pbw[s] (16 keys each) ----
        u32x4 pbw[4];
        #pragma unroll
        for (int s = 0; s < 4; ++s) {
          const int base = 8 * (s & 1);
          float e0, e1, e2, e3, e4, e5, e6, e7;
          if (s < 2) {
            e0=p0[base+0]; e1=p0[base+1]; e2=p0[base+2]; e3=p0[base+3];
            e4=p0[base+4]; e5=p0[base+5]; e6=p0[base+6]; e7=p0[base+7];
          } else {
            e0=p1[base+0]; e1=p1[base+1]; e2=p1[base+2]; e3=p1[base+3];
            e4=p1[base+4]; e5=p1[base+5]; e6=p1[base+6]; e7=p1[base+7];
          }
          const u32 w01 = pack2(e0, e1), w23 = pack2(e2, e3);
          const u32 w45 = pack2(e4, e5), w67 = pack2(e6, e7);
          // send the words destined for the partner half, receive ours
          const u32 sendA = g2 ? w01 : w45;
          const u32 sendB = g2 ? w23 : w67;
          const u32 recvA = (u32)__shfl_xor((int)sendA, 32, 64);
          const u32 recvB = (u32)__shfl_xor((int)sendB, 32, 64);
          pbw[s][0] = g2 ? recvA : w01;
          pbw[s][1] = g2 ? recvB : w23;
          pbw[s][2] = g2 ? w45 : recvA;
          pbw[s][3] = g2 ? w67 : recvB;
        }

        // ---- O^T += V^T * P^T ----
        const char* vb = (const char*)&vbuf[cur][0];
        __builtin_amdgcn_s_setprio(1);
        #pragma unroll
        for (int s = 0; s < 4; ++s) {
          const bf16x8 pv = __builtin_bit_cast(bf16x8, pbw[s]);
          bf16x8 aV0 = *(const bf16x8*)(vb + c * 128 + ((s * 32 + g2 * 16) ^ swz));
          bf16x8 aV1 = *(const bf16x8*)(vb + (32 + c) * 128 + ((s * 32 + g2 * 16) ^ swz));
          o0 = MFMA32(aV0, pv, o0);
          o1 = MFMA32(aV1, pv, o1);
        }
        __builtin_amdgcn_s_setprio(0);
      }
      asm volatile("" ::: "memory");
      __builtin_amdgcn_s_barrier();
    }

    // ---- normalize + store [b*T+q][h*64 + d] ----
    const float rinv = 1.f / l_run;
    const int q = qrow0 + c;
    u16* orow = Ob + ((long)b * SEQ + q) * DMODEL + h * DHEAD;
    #pragma unroll
    for (int m = 0; m < 4; ++m) {
      u16x4 v0, v1;
      #pragma unroll
      for (int e = 0; e < 4; ++e) {
        v0[e] = f2b(o0[4 * m + e] * rinv);
        v1[e] = f2b(o1[4 * m + e] * rinv);
      }
      const int d0 = 8 * m + 4 * g2;
      *(u16x4*)(orow + d0) = v0;
      *(u16x4*)(orow + 32 + d0) = v1;
    }
  }
}

extern "C" void kernel_launch(void* const* d_in, const int* in_sizes, int n_in,
                              void* d_out, int out_size, void* d_ws, size_t ws_size,
                              hipStream_t stream) {
  const float* x    = (const float*)d_in[0];
  // d_in[1] = mask (causal tril) — implemented implicitly
  const float* Wqkv = (const float*)d_in[2];
  const float* Wout = (const float*)d_in[3];
  float* out = (float*)d_out;
  char* ws = (char*)d_ws;
  u16* Xb  = (u16*)(ws + 0);          // 8192x1024 bf16      16,777,216
  u16* Wt1 = (u16*)(ws + 16777216);   // 3072x1024 bf16       6,291,456
  u16* Wt2 = (u16*)(ws + 23068672);   // 1024x1024 bf16       2,097,152
  u16* Qb  = (u16*)(ws + 25165824);   // [64][2048][64] bf16 16,777,216
  u16* Kb  = (u16*)(ws + 41943040);   // [64][2048][64] bf16 16,777,216
  u16* Vt  = (u16*)(ws + 58720256);   // [64][64][2048] bf16 16,777,216
  u16* Ob  = (u16*)(ws + 75497472);   // 8192x1024 bf16      16,777,216

  cvt_bf16_kernel<<<4096, 256, 0, stream>>>(x, Xb, BT * DMODEL / 8);
  transpose_cvt_kernel<<<dim3(96, 32), 256, 0, stream>>>(Wqkv, Wt1, DMODEL, 3 * DMODEL);
  transpose_cvt_kernel<<<dim3(32, 32), 256, 0, stream>>>(Wout, Wt2, DMODEL, DMODEL);
  gemm_bt_kernel<1><<<dim3(24, 64), 256, 0, stream>>>(
      Xb, Wt1, nullptr, Qb, Kb, Vt, BT, 3 * DMODEL, DMODEL);
  attn_kernel<<<dim3(64, 4), 512, 0, stream>>>(Qb, Kb, Vt, Ob);
  gemm_bt_kernel<0><<<dim3(8, 64), 256, 0, stream>>>(
      Ob, Wt2, out, nullptr, nullptr, nullptr, BT, DMODEL, DMODEL);
}